// Round 2
// baseline (180.792 us; speedup 1.0000x reference)
//
#include <hip/hip_runtime.h>

// WaveCell FDTD step, fp32, B=8, NY=NX=1024.
// y = inv*(8*h1 - (4-2b)*h2 + c^2*lap),  b = bg + rho/(1+h1^2),
// c = c_linear + 0.01*rho*h1^2, inv = 1/(4+2b), lap = 5pt zero-pad stencil.
// Outputs concatenated: [y (8M floats), h1 copy (8M floats)].
//
// R2: 4x grid-stride unroll (stride = 2 image planes -> same y/x4/masks/bg
// for all 4 iters), branchless clamped-address neighbor loads, nontemporal
// loads for stream-once h2/cl/rho, nontemporal stores, v_rcp_f32 for divides.

typedef float f4 __attribute__((ext_vector_type(4)));

#define NYDIM 1024
#define NX4   256      // float4 per row
#define UNROLL 4

__device__ __forceinline__ float wave_pt(float h1x, float h2x, float clx,
                                         float rx, float bgx, float lap) {
    float s   = h1x * h1x;
    float b   = bgx + rx * __builtin_amdgcn_rcpf(1.0f + s);
    float c   = clx + 0.01f * rx * s;
    float inv = __builtin_amdgcn_rcpf(4.0f + 2.0f * b);
    return inv * (8.0f * h1x - (4.0f - 2.0f * b) * h2x + c * c * lap);
}

__global__ __launch_bounds__(256) void wavecell_kernel(
    const float* __restrict__ h1,
    const f4*    __restrict__ h2,
    const f4*    __restrict__ cl,
    const f4*    __restrict__ rho,
    const f4*    __restrict__ bg,
    f4*          __restrict__ out,
    int n4)   // total float4 groups = B*NY*NX/4
{
    const int NT  = gridDim.x * blockDim.x;            // n4 / UNROLL
    const int tid = blockIdx.x * blockDim.x + threadIdx.x;
    const f4* h1v = (const f4*)h1;

    // Geometry is identical across the 4 strided iterations:
    // stride NT = n4/4 = 2*NY*NX4 float4s = exactly 2 image planes.
    const int x4 = tid & (NX4 - 1);
    const int y  = (tid >> 8) & (NYDIM - 1);
    const bool hasT = (y > 0), hasB = (y < NYDIM - 1);
    const bool hasL = (x4 > 0), hasR = (x4 < NX4 - 1);
    const int offT = hasT ? NX4 : 0;
    const int offB = hasB ? NX4 : 0;
    const int offL = hasL ? 1 : 0;
    const int offR = hasR ? 4 : 0;

    const f4 bgc = bg[(y << 8) | x4];

    int   gid[UNROLL];
    f4    hc[UNROLL], tp[UNROLL], bt[UNROLL], h2c[UNROLL], clc[UNROLL], rc[UNROLL];
    float lf[UNROLL], rt[UNROLL];

    #pragma unroll
    for (int i = 0; i < UNROLL; ++i) {
        int g = tid + i * NT;
        gid[i] = g;
        hc[i]  = h1v[g];
        tp[i]  = h1v[g - offT];          // clamped: loads own row when y==0
        bt[i]  = h1v[g + offB];
        lf[i]  = h1[4 * g - offL];
        rt[i]  = h1[4 * g + offR];
        h2c[i] = __builtin_nontemporal_load(h2 + g);
        clc[i] = __builtin_nontemporal_load(cl + g);
        rc[i]  = __builtin_nontemporal_load(rho + g);
    }

    #pragma unroll
    for (int i = 0; i < UNROLL; ++i) {
        const f4 z = {0.f, 0.f, 0.f, 0.f};
        f4 t  = hasT ? tp[i] : z;
        f4 b_ = hasB ? bt[i] : z;
        float L = hasL ? lf[i] : 0.0f;
        float R = hasR ? rt[i] : 0.0f;
        f4 c = hc[i];

        float lapx = t.x + b_.x + L   + c.y - 4.0f * c.x;
        float lapy = t.y + b_.y + c.x + c.z - 4.0f * c.y;
        float lapz = t.z + b_.z + c.y + c.w - 4.0f * c.z;
        float lapw = t.w + b_.w + c.z + R   - 4.0f * c.w;

        f4 yv;
        yv.x = wave_pt(c.x, h2c[i].x, clc[i].x, rc[i].x, bgc.x, lapx);
        yv.y = wave_pt(c.y, h2c[i].y, clc[i].y, rc[i].y, bgc.y, lapy);
        yv.z = wave_pt(c.z, h2c[i].z, clc[i].z, rc[i].z, bgc.z, lapz);
        yv.w = wave_pt(c.w, h2c[i].w, clc[i].w, rc[i].w, bgc.w, lapw);

        __builtin_nontemporal_store(yv, out + gid[i]);        // output 0: y
        __builtin_nontemporal_store(c,  out + n4 + gid[i]);   // output 1: h1
    }
}

extern "C" void kernel_launch(void* const* d_in, const int* in_sizes, int n_in,
                              void* d_out, int out_size, void* d_ws, size_t ws_size,
                              hipStream_t stream) {
    const float* h1  = (const float*)d_in[0];
    const f4*    h2  = (const f4*)d_in[1];
    const f4*    cl  = (const f4*)d_in[2];
    const f4*    rho = (const f4*)d_in[3];
    const f4*    bg  = (const f4*)d_in[4];
    f4* out = (f4*)d_out;

    int n  = in_sizes[0];          // 8*1024*1024
    int n4 = n / 4;                // 2,097,152 float4 groups
    int threads = 256;
    int blocks  = n4 / (threads * UNROLL);   // 2048
    wavecell_kernel<<<blocks, threads, 0, stream>>>(h1, h2, cl, rho, bg, out, n4);
}

// Round 3
// 169.568 us; speedup vs baseline: 1.0662x; 1.0662x over previous
//
#include <hip/hip_runtime.h>

// WaveCell FDTD step, fp32, B=8, NY=NX=1024.
// y = inv*(8*h1 - (4-2b)*h2 + c^2*lap),  b = bg + rho/(1+h1^2),
// c = c_linear + 0.01*rho*h1^2, inv = 1/(4+2b), lap = 5pt zero-pad stencil.
// Outputs concatenated: [y (8M floats), h1 copy (8M floats)].
//
// R3: LDS row-strip tiling. Block = 256 threads = one full 1024-wide row;
// each block computes R=8 rows, staging R+2 h1 rows (40 KB) in LDS so the
// vertical/horizontal stencil neighbors never re-hit the memory system.
// XCD swizzle: adjacent row-groups + the same bg slice stay on one XCD's L2
// (per-XCD L2s are not shared; round-robin dispatch otherwise triples h1
// fabric traffic). 4 blocks/CU (160 KB LDS), launch_bounds(256,4).

typedef float f4 __attribute__((ext_vector_type(4)));

#define NX4   256      // float4 per row
#define NYDIM 1024
#define RROWS 8        // center rows per block

__device__ __forceinline__ float wave_pt(float h1x, float h2x, float clx,
                                         float rx, float bgx, float lap) {
    float s   = h1x * h1x;
    float b   = bgx + rx * __builtin_amdgcn_rcpf(1.0f + s);
    float c   = clx + 0.01f * rx * s;
    float inv = __builtin_amdgcn_rcpf(4.0f + 2.0f * b);
    return inv * (8.0f * h1x - (4.0f - 2.0f * b) * h2x + c * c * lap);
}

__global__ __launch_bounds__(256, 4) void wavecell_kernel(
    const f4* __restrict__ h1,
    const f4* __restrict__ h2,
    const f4* __restrict__ cl,
    const f4* __restrict__ rho,
    const f4* __restrict__ bg,
    f4*       __restrict__ out,
    int n4)   // total float4 groups = B*NY*NX/4 = 2,097,152
{
    const int tid = threadIdx.x;          // f4-column 0..255
    // XCD swizzle: hw assigns block b -> XCD (b % 8). Map so each XCD gets
    // 16 consecutive row-groups x all 8 batches: bg slice 512 KB (8x reuse),
    // vertical halo neighbors co-resident in the same XCD L2.
    const int bi  = blockIdx.x;           // 0..1023
    const int xcd = bi & 7;
    const int j   = bi >> 3;              // 0..127
    const int rg  = (xcd << 4) | (j & 15);   // row-group 0..127
    const int bat = j >> 4;                  // batch 0..7
    const int r0  = rg << 3;                 // first center row
    const int planeBase = bat << 18;         // bat * NYDIM * NX4

    __shared__ f4 lds[RROWS + 2][NX4];

    // Stage R+2 h1 rows (zero-fill outside the image). gy uniform per k.
    #pragma unroll
    for (int k = 0; k < RROWS + 2; ++k) {
        int gy = r0 - 1 + k;
        f4 v = {0.f, 0.f, 0.f, 0.f};
        if (gy >= 0 && gy < NYDIM) v = h1[planeBase + (gy << 8) + tid];
        lds[k][tid] = v;
    }
    __syncthreads();

    const int xl = (tid > 0)       ? tid - 1 : 0;
    const int xr = (tid < NX4 - 1) ? tid + 1 : NX4 - 1;
    const bool hasL = (tid > 0), hasR = (tid < NX4 - 1);

    #pragma unroll
    for (int i = 0; i < RROWS; ++i) {
        const int gy = r0 + i;
        const int g  = planeBase + (gy << 8) + tid;

        // stream-once arrays: nontemporal
        f4 h2c = __builtin_nontemporal_load(h2 + g);
        f4 clc = __builtin_nontemporal_load(cl + g);
        f4 rc  = __builtin_nontemporal_load(rho + g);
        f4 bgc = bg[(gy << 8) + tid];     // L2-resident slice, keep cached

        f4 c  = lds[i + 1][tid];
        f4 t  = lds[i][tid];
        f4 bo = lds[i + 2][tid];
        f4 lg = lds[i + 1][xl];
        f4 rgp = lds[i + 1][xr];
        float L = hasL ? lg.w  : 0.0f;
        float R = hasR ? rgp.x : 0.0f;

        float lapx = t.x + bo.x + L   + c.y - 4.0f * c.x;
        float lapy = t.y + bo.y + c.x + c.z - 4.0f * c.y;
        float lapz = t.z + bo.z + c.y + c.w - 4.0f * c.z;
        float lapw = t.w + bo.w + c.z + R   - 4.0f * c.w;

        f4 yv;
        yv.x = wave_pt(c.x, h2c.x, clc.x, rc.x, bgc.x, lapx);
        yv.y = wave_pt(c.y, h2c.y, clc.y, rc.y, bgc.y, lapy);
        yv.z = wave_pt(c.z, h2c.z, clc.z, rc.z, bgc.z, lapz);
        yv.w = wave_pt(c.w, h2c.w, clc.w, rc.w, bgc.w, lapw);

        __builtin_nontemporal_store(yv, out + g);        // output 0: y
        __builtin_nontemporal_store(c,  out + n4 + g);   // output 1: h1
    }
}

extern "C" void kernel_launch(void* const* d_in, const int* in_sizes, int n_in,
                              void* d_out, int out_size, void* d_ws, size_t ws_size,
                              hipStream_t stream) {
    const f4* h1  = (const f4*)d_in[0];
    const f4* h2  = (const f4*)d_in[1];
    const f4* cl  = (const f4*)d_in[2];
    const f4* rho = (const f4*)d_in[3];
    const f4* bg  = (const f4*)d_in[4];
    f4* out = (f4*)d_out;

    int n  = in_sizes[0];          // 8*1024*1024
    int n4 = n / 4;                // 2,097,152 float4 groups
    // grid: 8 batches x 128 row-groups = 1024 blocks
    wavecell_kernel<<<1024, 256, 0, stream>>>(h1, h2, cl, rho, bg, out, n4);
}